// Round 9
// baseline (1372.118 us; speedup 1.0000x reference)
//
#include <hip/hip_runtime.h>
#include <hip/hip_bf16.h>
#include <math.h>

#define BB 8
#define NN 2048
#define KK 20
#define KP 24            // padded K stride: 96B rows, 16B-aligned for b128 reads
#define UPF 2
#define CIN 256
#define DD 64
#define COUTN 128
#define PHH 64
#define AHH 256
#define BN_INV 0.9999950000374997f   // np.float32(1/sqrt(1+1e-5))

typedef __hip_bfloat16 bf16;
typedef unsigned short u16;

static __device__ __forceinline__ float bf2f(const bf16 v) { return __bfloat162float(v); }
static __device__ __forceinline__ bf16  f2bf(const float v) { return __float2bfloat16(v); }

__global__ void sentinel_kernel(float* out) {
    if (threadIdx.x == 0 && blockIdx.x == 0) out[0] = 100.0f;
}

// ---------------------------------------------------------------------------
// Kernel 0: transpose ALL row-major weights into column-major f32 copies so
// every per-output-channel weight load is lane-coalesced.
// ---------------------------------------------------------------------------
__global__ __launch_bounds__(256) void prep_kernel(
    const float* __restrict__ Wa1, const float* __restrict__ Wp2,
    const float* __restrict__ Wend,
    const float* __restrict__ Wv1, const float* __restrict__ Wv2,
    const float* __restrict__ Wvs, const float* __restrict__ Wvv,
    const float* __restrict__ Wres,
    const float* __restrict__ Wk, const float* __restrict__ Wq,
    const float* __restrict__ Wu,
    float* __restrict__ Wa1T, float* __restrict__ Wp2T, float* __restrict__ WendT,
    float* __restrict__ Wv1T, float* __restrict__ Wv2T, float* __restrict__ WvsT,
    float* __restrict__ WvvT, float* __restrict__ WresT,
    float* __restrict__ WkT, float* __restrict__ WqT, float* __restrict__ WuT) {
    const int t = blockIdx.x * 256 + threadIdx.x;
    if (t < AHH * DD)        { int r = t / DD,  c = t % DD;  Wa1T[c * AHH + r]    = Wa1[t]; }
    if (t < PHH * PHH)       { int r = t / PHH, c = t % PHH; Wp2T[c * PHH + r]    = Wp2[t]; }
    if (t < COUTN * DD)      { int r = t / DD,  c = t % DD;  WendT[c * COUTN + r] = Wend[t]; }
    if (t < CIN * 2 * CIN)   { int r = t / (2*CIN), c = t % (2*CIN); Wv1T[c * CIN + r] = Wv1[t]; }
    if (t < CIN * CIN)       { int r = t / CIN, c = t % CIN; Wv2T[c * CIN + r]    = Wv2[t]; }
    if (t < CIN * 2 * CIN)   { int r = t / (2*CIN), c = t % (2*CIN); WvsT[c * CIN + r] = Wvs[t]; }
    if (t < DD * CIN)        { int r = t / CIN, c = t % CIN; WvvT[c * DD + r]     = Wvv[t]; }
    if (t < COUTN * CIN)     { int r = t / CIN, c = t % CIN; WresT[c * COUTN + r] = Wres[t]; }
    if (t < DD * CIN)        { int r = t / CIN, c = t % CIN; WkT[c * DD + r]      = Wk[t]; }
    if (t < DD * CIN)        { int r = t / CIN, c = t % CIN; WqT[c * DD + r]      = Wq[t]; }
    if (t < DD * CIN)        { int r = t / CIN, c = t % CIN; WuT[c * DD + r]      = Wu[t]; }
}

// ---------------------------------------------------------------------------
// Kernel 1: KNN (K=20 incl. self), exact fp32 reference formula (no FMA
// contraction), global (value, index)-lexicographic ordering == stable top_k.
// Per-thread contiguous 8-element tile -> b128 LDS reads in the argmin loop.
// ---------------------------------------------------------------------------
__global__ __launch_bounds__(256) void knn_kernel(const float* __restrict__ pos,
                                                  u16* __restrict__ idx_out,
                                                  float* __restrict__ posT) {
    __shared__ __align__(16) float dist[NN];
    __shared__ float rv[4];
    __shared__ int   ri[4];
    __shared__ int   sel[KK];
    __shared__ float q[3];
    const int b = blockIdx.x / NN;
    const int n = blockIdx.x % NN;
    const int t = threadIdx.x;
    const float* pb = pos + (size_t)b * 3 * NN;
    if (t < 3) {
        float v = pb[(size_t)t * NN + n];
        q[t] = v;
        posT[((size_t)b * NN + n) * 3 + t] = v;
    }
    __syncthreads();
    const float qx = q[0], qy = q[1], qz = q[2];
    const float sqq = __fadd_rn(__fadd_rn(__fmul_rn(qx, qx), __fmul_rn(qy, qy)), __fmul_rn(qz, qz));
    const int i8 = t * 8;
    {
        float xs[8], ys[8], zs[8], ds[8];
        *(float4*)&xs[0] = *(const float4*)&pb[i8];
        *(float4*)&xs[4] = *(const float4*)&pb[i8 + 4];
        *(float4*)&ys[0] = *(const float4*)&pb[NN + i8];
        *(float4*)&ys[4] = *(const float4*)&pb[NN + i8 + 4];
        *(float4*)&zs[0] = *(const float4*)&pb[2 * NN + i8];
        *(float4*)&zs[4] = *(const float4*)&pb[2 * NN + i8 + 4];
#pragma unroll
        for (int j = 0; j < 8; ++j) {
            float px = xs[j], py = ys[j], pz = zs[j];
            float sqm = __fadd_rn(__fadd_rn(__fmul_rn(px, px), __fmul_rn(py, py)), __fmul_rn(pz, pz));
            float dt  = __fadd_rn(__fadd_rn(__fmul_rn(qx, px), __fmul_rn(qy, py)), __fmul_rn(qz, pz));
            ds[j] = __fsub_rn(__fadd_rn(sqq, sqm), __fmul_rn(2.0f, dt));
        }
        *(float4*)&dist[i8]     = *(float4*)&ds[0];
        *(float4*)&dist[i8 + 4] = *(float4*)&ds[4];
    }
    __syncthreads();
    for (int it = 0; it < KK; ++it) {
        float d[8];
        *(float4*)&d[0] = *(const float4*)&dist[i8];
        *(float4*)&d[4] = *(const float4*)&dist[i8 + 4];
        float bv = d[0];
        int   bi = i8;
#pragma unroll
        for (int j = 1; j < 8; ++j) {
            if (d[j] < bv) { bv = d[j]; bi = i8 + j; }   // ascending keeps lowest idx on ties
        }
        for (int off = 32; off > 0; off >>= 1) {
            float v2 = __shfl_down(bv, off, 64);
            int   i2 = __shfl_down(bi, off, 64);
            if (v2 < bv || (v2 == bv && i2 < bi)) { bv = v2; bi = i2; }
        }
        if ((t & 63) == 0) { rv[t >> 6] = bv; ri[t >> 6] = bi; }
        __syncthreads();
        if (t == 0) {
            float v0 = rv[0]; int i0 = ri[0];
            for (int w = 1; w < 4; ++w) {
                if (rv[w] < v0 || (rv[w] == v0 && ri[w] < i0)) { v0 = rv[w]; i0 = ri[w]; }
            }
            sel[it] = i0;
            dist[i0] = 3.4e38f;
        }
        __syncthreads();
    }
    if (t < KK) idx_out[((size_t)b * NN + n) * KK + t] = (u16)sel[t];
}

// ---------------------------------------------------------------------------
// Kernel 2: value = MLP_Res(concat(key,query)) in LDS; coalesced transposed
// weights, float4 LDS reads. Emits vf (B,N,64) and resid (B,N,128) bf16.
// ---------------------------------------------------------------------------
__global__ __launch_bounds__(256) void value_kernel(
    const float* __restrict__ key_feat, const float* __restrict__ query_feat,
    const float* __restrict__ Wv1T, const float* __restrict__ bv1,
    const float* __restrict__ Wv2T, const float* __restrict__ bv2,
    const float* __restrict__ WvsT, const float* __restrict__ bvs,
    const float* __restrict__ WvvT, const float* __restrict__ bvv,
    const float* __restrict__ WresT, const float* __restrict__ bres,
    bf16* __restrict__ vf_ws, bf16* __restrict__ resid_ws) {
    __shared__ __align__(16) float xcol[2 * CIN][8];
    __shared__ __align__(16) float hid[CIN][8];
    __shared__ __align__(16) float val[CIN][8];
    const int b  = blockIdx.x / (NN / 8);
    const int n0 = (blockIdx.x % (NN / 8)) * 8;
    const int t  = threadIdx.x;
    const float* kfp = key_feat + (size_t)b * CIN * NN;
    const float* qfp = query_feat + (size_t)b * CIN * NN;
    for (int u = t; u < 2 * CIN * 8; u += 256) {
        int c = u >> 3, j = u & 7;
        xcol[c][j] = (c < CIN) ? kfp[(size_t)c * NN + n0 + j]
                               : qfp[(size_t)(c - CIN) * NN + n0 + j];
    }
    __syncthreads();
    const int o = t;
    float acc[8];
#pragma unroll
    for (int j = 0; j < 8; ++j) acc[j] = 0.f;
    for (int c = 0; c < 2 * CIN; ++c) {
        float w = Wv1T[(size_t)c * CIN + o];
        const float4* x4 = (const float4*)(&xcol[c][0]);
        float4 x0 = x4[0], x1 = x4[1];
        acc[0] += w * x0.x; acc[1] += w * x0.y; acc[2] += w * x0.z; acc[3] += w * x0.w;
        acc[4] += w * x1.x; acc[5] += w * x1.y; acc[6] += w * x1.z; acc[7] += w * x1.w;
    }
    const float b1 = bv1[o];
#pragma unroll
    for (int j = 0; j < 8; ++j) hid[o][j] = fmaxf(acc[j] + b1, 0.f);
    __syncthreads();
    float acc2[8];
#pragma unroll
    for (int j = 0; j < 8; ++j) acc2[j] = 0.f;
    for (int c = 0; c < CIN; ++c) {
        float w = Wv2T[(size_t)c * CIN + o];
        const float4* h4 = (const float4*)(&hid[c][0]);
        float4 h0 = h4[0], h1 = h4[1];
        acc2[0] += w * h0.x; acc2[1] += w * h0.y; acc2[2] += w * h0.z; acc2[3] += w * h0.w;
        acc2[4] += w * h1.x; acc2[5] += w * h1.y; acc2[6] += w * h1.z; acc2[7] += w * h1.w;
    }
    for (int c = 0; c < 2 * CIN; ++c) {
        float w = WvsT[(size_t)c * CIN + o];
        const float4* x4 = (const float4*)(&xcol[c][0]);
        float4 x0 = x4[0], x1 = x4[1];
        acc2[0] += w * x0.x; acc2[1] += w * x0.y; acc2[2] += w * x0.z; acc2[3] += w * x0.w;
        acc2[4] += w * x1.x; acc2[5] += w * x1.y; acc2[6] += w * x1.z; acc2[7] += w * x1.w;
    }
    const float bb = bv2[o] + bvs[o];
#pragma unroll
    for (int j = 0; j < 8; ++j) val[o][j] = acc2[j] + bb;
    __syncthreads();
    // vf: lane = output column (coalesced WvvT)
    {
        const int o2 = t & 63, jg = t >> 6;          // jg in 0..3 -> j = jg, jg+4
        float a0 = 0.f, a1 = 0.f;
        for (int c = 0; c < CIN; ++c) {
            float w = WvvT[(size_t)c * DD + o2];
            a0 += w * val[c][jg];
            a1 += w * val[c][jg + 4];
        }
        const float bo = bvv[o2];
        vf_ws[((size_t)b * NN + n0 + jg) * DD + o2]     = f2bf(a0 + bo);
        vf_ws[((size_t)b * NN + n0 + jg + 4) * DD + o2] = f2bf(a1 + bo);
    }
    // resid: lane = output column (coalesced WresT)
    {
        const int o3 = t & 127, jg = t >> 7;         // jg in 0..1 -> j = jg, jg+2, jg+4, jg+6
        float a0 = 0.f, a1 = 0.f, a2 = 0.f, a3 = 0.f;
        for (int c = 0; c < CIN; ++c) {
            float w = WresT[(size_t)c * COUTN + o3];
            a0 += w * val[c][jg];
            a1 += w * val[c][jg + 2];
            a2 += w * val[c][jg + 4];
            a3 += w * val[c][jg + 6];
        }
        const float bo = bres[o3];
        resid_ws[((size_t)b * NN + n0 + jg) * COUTN + o3]     = f2bf(a0 + bo);
        resid_ws[((size_t)b * NN + n0 + jg + 2) * COUTN + o3] = f2bf(a1 + bo);
        resid_ws[((size_t)b * NN + n0 + jg + 4) * COUTN + o3] = f2bf(a2 + bo);
        resid_ws[((size_t)b * NN + n0 + jg + 6) * COUTN + o3] = f2bf(a3 + bo);
    }
}

// ---------------------------------------------------------------------------
// Kernel 3: kf/qf/uf projections -> (B,N,64) bf16 n-major, transposed weights.
// ---------------------------------------------------------------------------
__global__ __launch_bounds__(256) void proj_kernel(
    const float* __restrict__ key_feat, const float* __restrict__ query_feat,
    const float* __restrict__ upfeat,
    const float* __restrict__ WkT, const float* __restrict__ bk,
    const float* __restrict__ WqT, const float* __restrict__ bq,
    const float* __restrict__ WuT, const float* __restrict__ bu,
    bf16* __restrict__ kf, bf16* __restrict__ qf, bf16* __restrict__ uf) {
    __shared__ __align__(16) float xcol[CIN][16];
    const int p  = blockIdx.y;
    const int b  = blockIdx.x / (NN / 16);
    const int n0 = (blockIdx.x % (NN / 16)) * 16;
    const int t  = threadIdx.x;
    const float* WT; const float* bias; bf16* out; const float* xin;
    if (p == 0)      { WT = WkT; bias = bk; out = kf; xin = key_feat; }
    else if (p == 1) { WT = WqT; bias = bq; out = qf; xin = query_feat; }
    else             { WT = WuT; bias = bu; out = uf; xin = upfeat; }
    const float* xp = xin + (size_t)b * CIN * NN;
    for (int u = t; u < CIN * 16; u += 256) {
        int c = u >> 4, j = u & 15;
        xcol[c][j] = xp[(size_t)c * NN + n0 + j];
    }
    __syncthreads();
    const int o = t & 63, jg = t >> 6;
    float acc[4] = {0.f, 0.f, 0.f, 0.f};
    for (int c = 0; c < CIN; ++c) {
        float w = WT[(size_t)c * DD + o];
        const float4* x4 = (const float4*)(&xcol[c][jg * 4]);
        float4 xv = x4[0];
        acc[0] += w * xv.x; acc[1] += w * xv.y; acc[2] += w * xv.z; acc[3] += w * xv.w;
    }
    const float bb = bias[o];
#pragma unroll
    for (int jj = 0; jj < 4; ++jj)
        out[((size_t)b * NN + n0 + jg * 4 + jj) * DD + o] = f2bf(acc[jj] + bb);
}

// ---------------------------------------------------------------------------
// Kernel 4: fused per-(b,n) attention. Register-blocked phases E (2 hr rows,
// c-split via t&1 + shfl_xor) and F (2 cr cols, quarter-hh via t&3 +
// shfl_xor) to halve LDS b128 instruction count.
// ---------------------------------------------------------------------------
__global__ __launch_bounds__(256) void attn_kernel(
    const float* __restrict__ posT, const u16* __restrict__ idx_ws,
    const bf16* __restrict__ kf_ws, const bf16* __restrict__ qf_ws,
    const bf16* __restrict__ uf_ws, const bf16* __restrict__ vf_ws,
    const bf16* __restrict__ resid_ws,
    const float* __restrict__ Wp1, const float* __restrict__ bp1,
    const float* __restrict__ gp1, const float* __restrict__ betap1,
    const float* __restrict__ Wp2T, const float* __restrict__ bp2,
    const float* __restrict__ Wa1T, const float* __restrict__ ba1,
    const float* __restrict__ ga1, const float* __restrict__ betaa1,
    const float* __restrict__ Wt, const float* __restrict__ bt,
    const float* __restrict__ WendT, const float* __restrict__ bend,
    float* __restrict__ out) {
    __shared__ int   nidx[KK];
    __shared__ float prel[KK][3];
    __shared__ float qcol[DD], ucol[DD];
    __shared__ float residc[COUTN];
    __shared__ __align__(16) float ph[KK][PHH];      // 5 KB
    __shared__ __align__(16) float pe[KK][DD];       // 5 KB
    __shared__ __align__(16) float sbuf[DD][KP];     // 6 KB
    __shared__ __align__(16) float vbuf[DD][KP];     // 6 KB
    __shared__ __align__(16) float hbuf[AHH][KP];    // 24 KB
    __shared__ float agg[2 * DD];

    const int b = blockIdx.x / NN;
    const int n = blockIdx.x % NN;
    const int t = threadIdx.x;
    const size_t row = (size_t)b * NN + n;

    if (t < KK) nidx[t] = (int)idx_ws[row * KK + t];
    __syncthreads();

    // phase A: loads + contiguous gathers
    if (t < DD)                qcol[t]        = bf2f(qf_ws[row * DD + t]);
    else if (t < 2 * DD)       ucol[t - DD]   = bf2f(uf_ws[row * DD + (t - DD)]);
    else                       residc[t - 2 * DD] = bf2f(resid_ws[row * COUTN + (t - 2 * DD)]);
    if (t < KK * 3) {
        int k = t / 3, d = t % 3;
        prel[k][d] = posT[row * 3 + d] - posT[((size_t)b * NN + nidx[k]) * 3 + d];
    }
    for (int u = t; u < KK * DD; u += 256) {
        int k = u >> 6, c = u & 63;
        size_t nb = ((size_t)b * NN + nidx[k]) * DD + c;
        float un = bf2f(uf_ws[nb]);
        sbuf[c][k] = -(bf2f(kf_ws[nb]) + un);
        vbuf[c][k] = bf2f(vf_ws[nb]) - un;
    }
    __syncthreads();

    // phase B: pos_mlp layer 1 (3 -> 64, BN, ReLU)
    for (int u = t; u < KK * PHH; u += 256) {
        int k = u >> 6, c = u & 63;
        float a = Wp1[c * 3 + 0] * prel[k][0]
                + Wp1[c * 3 + 1] * prel[k][1]
                + Wp1[c * 3 + 2] * prel[k][2]
                + bp1[c];
        a = gp1[c] * a * BN_INV + betap1[c];
        ph[k][c] = fmaxf(a, 0.f);
    }
    __syncthreads();

    // phase C: pos_mlp layer 2 (64 -> 64); ph rows read as float4
    for (int u = t; u < KK * DD; u += 256) {
        int k = u >> 6, c = u & 63;
        float a = 0.f;
        const float4* p4 = (const float4*)(&ph[k][0]);
#pragma unroll
        for (int j4 = 0; j4 < PHH / 4; ++j4) {
            float4 pv = p4[j4];
            a += Wp2T[(j4 * 4 + 0) * DD + c] * pv.x;
            a += Wp2T[(j4 * 4 + 1) * DD + c] * pv.y;
            a += Wp2T[(j4 * 4 + 2) * DD + c] * pv.z;
            a += Wp2T[(j4 * 4 + 3) * DD + c] * pv.w;
        }
        pe[k][c] = a + bp2[c];
    }
    __syncthreads();

    // phase D: combine -> s = q - k + pe + (u - un); v = vf_n + pe + (u - un)
    for (int u = t; u < KK * DD; u += 256) {
        int k = u >> 6, c = u & 63;
        float add = ucol[c] + pe[k][c];
        sbuf[c][k] += qcol[c] + add;
        vbuf[c][k] += add;
    }
    __syncthreads();

    // phase E: h = relu(bn(Wa1 @ s + ba1)); thread handles rows (p, p+128),
    // c-range split by t&1, partial sums combined via shfl_xor(1).
    {
        const int p   = t >> 1;           // 0..127
        const int hr0 = p, hr1 = p + 128;
        const int cb  = (t & 1) * 32;
        float acc0[KK], acc1[KK];
#pragma unroll
        for (int k = 0; k < KK; ++k) { acc0[k] = 0.f; acc1[k] = 0.f; }
        for (int ci = 0; ci < 32; ++ci) {
            const int c = cb + ci;
            float w0 = Wa1T[c * AHH + hr0];
            float w1 = Wa1T[c * AHH + hr1];
            const float4* s4 = (const float4*)(&sbuf[c][0]);
#pragma unroll
            for (int j = 0; j < 5; ++j) {
                float4 sv = s4[j];
                acc0[4 * j + 0] += w0 * sv.x; acc1[4 * j + 0] += w1 * sv.x;
                acc0[4 * j + 1] += w0 * sv.y; acc1[4 * j + 1] += w1 * sv.y;
                acc0[4 * j + 2] += w0 * sv.z; acc1[4 * j + 2] += w1 * sv.z;
                acc0[4 * j + 3] += w0 * sv.w; acc1[4 * j + 3] += w1 * sv.w;
            }
        }
#pragma unroll
        for (int k = 0; k < KK; ++k) {
            acc0[k] += __shfl_xor(acc0[k], 1, 64);
            acc1[k] += __shfl_xor(acc1[k], 1, 64);
        }
        const int hr = (t & 1) ? hr1 : hr0;
        const float* accp = (t & 1) ? acc1 : acc0;
        const float bb = ba1[hr];
        const float g  = ga1[hr];
        const float be = betaa1[hr];
        float4* hrow = (float4*)(&hbuf[hr][0]);
#pragma unroll
        for (int j = 0; j < 5; ++j) {
            float4 hv;
            hv.x = fmaxf(g * (accp[4 * j + 0] + bb) * BN_INV + be, 0.f);
            hv.y = fmaxf(g * (accp[4 * j + 1] + bb) * BN_INV + be, 0.f);
            hv.z = fmaxf(g * (accp[4 * j + 2] + bb) * BN_INV + be, 0.f);
            hv.w = fmaxf(g * (accp[4 * j + 3] + bb) * BN_INV + be, 0.f);
            hrow[j] = hv;
        }
    }
    __syncthreads();

    // phase F: logits + softmax + aggregate; thread handles (cr, cr+64),
    // hh-range quarter by t&3, combined via shfl_xor(1),(2).
    {
        const int pair = t >> 2;          // 0..63
        const int cr0 = pair, cr1 = pair + 64;
        const int quarter = t & 3;
        float acc0[KK], acc1[KK];
#pragma unroll
        for (int k = 0; k < KK; ++k) { acc0[k] = 0.f; acc1[k] = 0.f; }
        for (int i = 0; i < 64; ++i) {
            const int hh = (i << 2) | quarter;
            float w0 = Wt[(size_t)hh * 128 + cr0];
            float w1 = Wt[(size_t)hh * 128 + cr1];
            const float4* h4 = (const float4*)(&hbuf[hh][0]);
#pragma unroll
            for (int j = 0; j < 5; ++j) {
                float4 hv = h4[j];
                acc0[4 * j + 0] += w0 * hv.x; acc1[4 * j + 0] += w1 * hv.x;
                acc0[4 * j + 1] += w0 * hv.y; acc1[4 * j + 1] += w1 * hv.y;
                acc0[4 * j + 2] += w0 * hv.z; acc1[4 * j + 2] += w1 * hv.z;
                acc0[4 * j + 3] += w0 * hv.w; acc1[4 * j + 3] += w1 * hv.w;
            }
        }
#pragma unroll
        for (int k = 0; k < KK; ++k) {
            acc0[k] += __shfl_xor(acc0[k], 1, 64);
            acc0[k] += __shfl_xor(acc0[k], 2, 64);
            acc1[k] += __shfl_xor(acc1[k], 1, 64);
            acc1[k] += __shfl_xor(acc1[k], 2, 64);
        }
        if (quarter == 0 || quarter == 1) {
            const int   cr  = (quarter == 0) ? cr0 : cr1;
            float*      acc = (quarter == 0) ? acc0 : acc1;
            const float bb  = bt[cr >> 1];
#pragma unroll
            for (int k = 0; k < KK; ++k) acc[k] += bb;
            float m = acc[0];
#pragma unroll
            for (int k = 1; k < KK; ++k) m = fmaxf(m, acc[k]);
            float sum = 0.f;
#pragma unroll
            for (int k = 0; k < KK; ++k) { acc[k] = expf(acc[k] - m); sum += acc[k]; }
            const float invs = 1.f / sum;
            const int c = cr >> 1;
            const float4* v4 = (const float4*)(&vbuf[c][0]);
            float a = 0.f;
#pragma unroll
            for (int j = 0; j < 5; ++j) {
                float4 vv = v4[j];
                a += (acc[4 * j + 0] * invs) * vv.x;
                a += (acc[4 * j + 1] * invs) * vv.y;
                a += (acc[4 * j + 2] * invs) * vv.z;
                a += (acc[4 * j + 3] * invs) * vv.w;
            }
            agg[cr] = a;
        }
    }
    __syncthreads();

    // phase G: conv_end + residual -> f32 out[b][o][2n+r]; WendT coalesced
    {
        const int o = t & 127, r = t >> 7;
        float acc = bend[o];
        for (int c = 0; c < DD; ++c) acc += WendT[c * COUTN + o] * agg[c * 2 + r];
        out[(size_t)b * COUTN * (NN * UPF) + (size_t)o * (NN * UPF) + 2 * n + r] =
            acc + residc[o];
    }
}

extern "C" void kernel_launch(void* const* d_in, const int* in_sizes, int n_in,
                              void* d_out, int out_size, void* d_ws, size_t ws_size,
                              hipStream_t stream) {
    const float* pos        = (const float*)d_in[0];
    const float* key_feat   = (const float*)d_in[1];
    const float* query_feat = (const float*)d_in[2];
    const float* upfeat     = (const float*)d_in[3];
    const float* Wv1 = (const float*)d_in[4];
    const float* bv1 = (const float*)d_in[5];
    const float* Wv2 = (const float*)d_in[6];
    const float* bv2 = (const float*)d_in[7];
    const float* Wvs = (const float*)d_in[8];
    const float* bvs = (const float*)d_in[9];
    const float* Wk  = (const float*)d_in[10];
    const float* bk  = (const float*)d_in[11];
    const float* Wq  = (const float*)d_in[12];
    const float* bq  = (const float*)d_in[13];
    const float* Wvv = (const float*)d_in[14];
    const float* bvv = (const float*)d_in[15];
    const float* Wu  = (const float*)d_in[16];
    const float* bu  = (const float*)d_in[17];
    const float* Wp1 = (const float*)d_in[18];
    const float* bp1 = (const float*)d_in[19];
    const float* gp1 = (const float*)d_in[20];
    const float* betap1 = (const float*)d_in[21];
    const float* Wp2 = (const float*)d_in[22];
    const float* bp2 = (const float*)d_in[23];
    const float* Wa1 = (const float*)d_in[24];
    const float* ba1 = (const float*)d_in[25];
    const float* ga1 = (const float*)d_in[26];
    const float* betaa1 = (const float*)d_in[27];
    const float* Wt   = (const float*)d_in[28];
    const float* bt   = (const float*)d_in[29];
    const float* Wend = (const float*)d_in[30];
    const float* bend = (const float*)d_in[31];
    const float* Wres = (const float*)d_in[32];
    const float* bres = (const float*)d_in[33];
    float* out = (float*)d_out;
    (void)out_size;

    const bool sizes_ok = (n_in >= 34)
        && (in_sizes[0] == BB * 3 * NN)
        && (in_sizes[1] == BB * CIN * NN)
        && (in_sizes[4] == CIN * 2 * CIN)
        && (in_sizes[28] == AHH * DD * UPF)
        && (in_sizes[32] == COUTN * CIN);

    // Workspace layout (256B-aligned), total ~14.7 MB.
    size_t off = 0;
    auto take = [&](size_t bytes) { size_t o = off; off = (off + bytes + 255) & ~(size_t)255; return o; };
    const size_t off_posT  = take((size_t)BB * NN * 3 * sizeof(float));
    const size_t off_idx   = take((size_t)BB * NN * KK * sizeof(u16));
    const size_t off_vf    = take((size_t)BB * NN * DD * sizeof(bf16));
    const size_t off_kf    = take((size_t)BB * NN * DD * sizeof(bf16));
    const size_t off_qf    = take((size_t)BB * NN * DD * sizeof(bf16));
    const size_t off_uf    = take((size_t)BB * NN * DD * sizeof(bf16));
    const size_t off_resid = take((size_t)BB * NN * COUTN * sizeof(bf16));
    const size_t off_wa1t  = take((size_t)AHH * DD * sizeof(float));
    const size_t off_wp2t  = take((size_t)PHH * PHH * sizeof(float));
    const size_t off_wendt = take((size_t)COUTN * DD * sizeof(float));
    const size_t off_wv1t  = take((size_t)CIN * 2 * CIN * sizeof(float));
    const size_t off_wv2t  = take((size_t)CIN * CIN * sizeof(float));
    const size_t off_wvst  = take((size_t)CIN * 2 * CIN * sizeof(float));
    const size_t off_wvvt  = take((size_t)DD * CIN * sizeof(float));
    const size_t off_wrest = take((size_t)COUTN * CIN * sizeof(float));
    const size_t off_wkt   = take((size_t)DD * CIN * sizeof(float));
    const size_t off_wqt   = take((size_t)DD * CIN * sizeof(float));
    const size_t off_wut   = take((size_t)DD * CIN * sizeof(float));
    const size_t NEED = off;

    if (!sizes_ok) return;                       // untouched zeros => shape assumption wrong
    if (ws_size < NEED) {                        // absmax ~100 => ws too small, back off next round
        sentinel_kernel<<<1, 64, 0, stream>>>(out);
        return;
    }

    char* ws = (char*)d_ws;
    float* posT_ws  = (float*)(ws + off_posT);
    u16*   idx_ws   = (u16*)(ws + off_idx);
    bf16*  vf_ws    = (bf16*)(ws + off_vf);
    bf16*  kf_ws    = (bf16*)(ws + off_kf);
    bf16*  qf_ws    = (bf16*)(ws + off_qf);
    bf16*  uf_ws    = (bf16*)(ws + off_uf);
    bf16*  resid_ws = (bf16*)(ws + off_resid);
    float* Wa1T_ws  = (float*)(ws + off_wa1t);
    float* Wp2T_ws  = (float*)(ws + off_wp2t);
    float* WendT_ws = (float*)(ws + off_wendt);
    float* Wv1T_ws  = (float*)(ws + off_wv1t);
    float* Wv2T_ws  = (float*)(ws + off_wv2t);
    float* WvsT_ws  = (float*)(ws + off_wvst);
    float* WvvT_ws  = (float*)(ws + off_wvvt);
    float* WresT_ws = (float*)(ws + off_wrest);
    float* WkT_ws   = (float*)(ws + off_wkt);
    float* WqT_ws   = (float*)(ws + off_wqt);
    float* WuT_ws   = (float*)(ws + off_wut);

    prep_kernel<<<(CIN * 2 * CIN + 255) / 256, 256, 0, stream>>>(
        Wa1, Wp2, Wend, Wv1, Wv2, Wvs, Wvv, Wres, Wk, Wq, Wu,
        Wa1T_ws, Wp2T_ws, WendT_ws, Wv1T_ws, Wv2T_ws, WvsT_ws,
        WvvT_ws, WresT_ws, WkT_ws, WqT_ws, WuT_ws);
    knn_kernel<<<BB * NN, 256, 0, stream>>>(pos, idx_ws, posT_ws);
    value_kernel<<<BB * (NN / 8), 256, 0, stream>>>(key_feat, query_feat,
        Wv1T_ws, bv1, Wv2T_ws, bv2, WvsT_ws, bvs, WvvT_ws, bvv, WresT_ws, bres,
        vf_ws, resid_ws);
    proj_kernel<<<dim3(BB * (NN / 16), 3), 256, 0, stream>>>(key_feat, query_feat, upfeat,
        WkT_ws, bk, WqT_ws, bq, WuT_ws, bu, kf_ws, qf_ws, uf_ws);
    attn_kernel<<<BB * NN, 256, 0, stream>>>(posT_ws, idx_ws,
        kf_ws, qf_ws, uf_ws, vf_ws, resid_ws,
        Wp1, bp1, gp1, betap1, Wp2T_ws, bp2, Wa1T_ws, ba1, ga1, betaa1, Wt, bt,
        WendT_ws, bend, out);
}

// Round 10
// 1363.536 us; speedup vs baseline: 1.0063x; 1.0063x over previous
//
#include <hip/hip_runtime.h>
#include <hip/hip_bf16.h>
#include <math.h>

#define BB 8
#define NN 2048
#define KK 20
#define KP 24            // padded K stride: 2 k-halves x 12 floats, 16B-aligned
#define UPF 2
#define CIN 256
#define DD 64
#define COUTN 128
#define PHH 64
#define AHH 256
#define BN_INV 0.9999950000374997f   // np.float32(1/sqrt(1+1e-5))

typedef __hip_bfloat16 bf16;
typedef unsigned short u16;

static __device__ __forceinline__ float bf2f(const bf16 v) { return __bfloat162float(v); }
static __device__ __forceinline__ bf16  f2bf(const float v) { return __float2bfloat16(v); }

__global__ void sentinel_kernel(float* out) {
    if (threadIdx.x == 0 && blockIdx.x == 0) out[0] = 100.0f;
}

// ---------------------------------------------------------------------------
// Kernel 0: transpose ALL row-major weights into column-major f32 copies.
// ---------------------------------------------------------------------------
__global__ __launch_bounds__(256) void prep_kernel(
    const float* __restrict__ Wa1, const float* __restrict__ Wp2,
    const float* __restrict__ Wend,
    const float* __restrict__ Wv1, const float* __restrict__ Wv2,
    const float* __restrict__ Wvs, const float* __restrict__ Wvv,
    const float* __restrict__ Wres,
    const float* __restrict__ Wk, const float* __restrict__ Wq,
    const float* __restrict__ Wu,
    float* __restrict__ Wa1T, float* __restrict__ Wp2T, float* __restrict__ WendT,
    float* __restrict__ Wv1T, float* __restrict__ Wv2T, float* __restrict__ WvsT,
    float* __restrict__ WvvT, float* __restrict__ WresT,
    float* __restrict__ WkT, float* __restrict__ WqT, float* __restrict__ WuT) {
    const int t = blockIdx.x * 256 + threadIdx.x;
    if (t < AHH * DD)        { int r = t / DD,  c = t % DD;  Wa1T[c * AHH + r]    = Wa1[t]; }
    if (t < PHH * PHH)       { int r = t / PHH, c = t % PHH; Wp2T[c * PHH + r]    = Wp2[t]; }
    if (t < COUTN * DD)      { int r = t / DD,  c = t % DD;  WendT[c * COUTN + r] = Wend[t]; }
    if (t < CIN * 2 * CIN)   { int r = t / (2*CIN), c = t % (2*CIN); Wv1T[c * CIN + r] = Wv1[t]; }
    if (t < CIN * CIN)       { int r = t / CIN, c = t % CIN; Wv2T[c * CIN + r]    = Wv2[t]; }
    if (t < CIN * 2 * CIN)   { int r = t / (2*CIN), c = t % (2*CIN); WvsT[c * CIN + r] = Wvs[t]; }
    if (t < DD * CIN)        { int r = t / CIN, c = t % CIN; WvvT[c * DD + r]     = Wvv[t]; }
    if (t < COUTN * CIN)     { int r = t / CIN, c = t % CIN; WresT[c * COUTN + r] = Wres[t]; }
    if (t < DD * CIN)        { int r = t / CIN, c = t % CIN; WkT[c * DD + r]      = Wk[t]; }
    if (t < DD * CIN)        { int r = t / CIN, c = t % CIN; WqT[c * DD + r]      = Wq[t]; }
    if (t < DD * CIN)        { int r = t / CIN, c = t % CIN; WuT[c * DD + r]      = Wu[t]; }
}

// ---------------------------------------------------------------------------
// Kernel 1: KNN (K=20 incl. self), exact fp32 reference formula (no FMA
// contraction), lexicographic (value,index) ordering == stable top_k.
// ---------------------------------------------------------------------------
__global__ __launch_bounds__(256) void knn_kernel(const float* __restrict__ pos,
                                                  u16* __restrict__ idx_out,
                                                  float* __restrict__ posT) {
    __shared__ __align__(16) float dist[NN];
    __shared__ float rv[4];
    __shared__ int   ri[4];
    __shared__ int   sel[KK];
    __shared__ float q[3];
    const int b = blockIdx.x / NN;
    const int n = blockIdx.x % NN;
    const int t = threadIdx.x;
    const float* pb = pos + (size_t)b * 3 * NN;
    if (t < 3) {
        float v = pb[(size_t)t * NN + n];
        q[t] = v;
        posT[((size_t)b * NN + n) * 3 + t] = v;
    }
    __syncthreads();
    const float qx = q[0], qy = q[1], qz = q[2];
    const float sqq = __fadd_rn(__fadd_rn(__fmul_rn(qx, qx), __fmul_rn(qy, qy)), __fmul_rn(qz, qz));
    const int i8 = t * 8;
    {
        float xs[8], ys[8], zs[8], ds[8];
        *(float4*)&xs[0] = *(const float4*)&pb[i8];
        *(float4*)&xs[4] = *(const float4*)&pb[i8 + 4];
        *(float4*)&ys[0] = *(const float4*)&pb[NN + i8];
        *(float4*)&ys[4] = *(const float4*)&pb[NN + i8 + 4];
        *(float4*)&zs[0] = *(const float4*)&pb[2 * NN + i8];
        *(float4*)&zs[4] = *(const float4*)&pb[2 * NN + i8 + 4];
#pragma unroll
        for (int j = 0; j < 8; ++j) {
            float px = xs[j], py = ys[j], pz = zs[j];
            float sqm = __fadd_rn(__fadd_rn(__fmul_rn(px, px), __fmul_rn(py, py)), __fmul_rn(pz, pz));
            float dt  = __fadd_rn(__fadd_rn(__fmul_rn(qx, px), __fmul_rn(qy, py)), __fmul_rn(qz, pz));
            ds[j] = __fsub_rn(__fadd_rn(sqq, sqm), __fmul_rn(2.0f, dt));
        }
        *(float4*)&dist[i8]     = *(float4*)&ds[0];
        *(float4*)&dist[i8 + 4] = *(float4*)&ds[4];
    }
    __syncthreads();
    for (int it = 0; it < KK; ++it) {
        float d[8];
        *(float4*)&d[0] = *(const float4*)&dist[i8];
        *(float4*)&d[4] = *(const float4*)&dist[i8 + 4];
        float bv = d[0];
        int   bi = i8;
#pragma unroll
        for (int j = 1; j < 8; ++j) {
            if (d[j] < bv) { bv = d[j]; bi = i8 + j; }
        }
        for (int off = 32; off > 0; off >>= 1) {
            float v2 = __shfl_down(bv, off, 64);
            int   i2 = __shfl_down(bi, off, 64);
            if (v2 < bv || (v2 == bv && i2 < bi)) { bv = v2; bi = i2; }
        }
        if ((t & 63) == 0) { rv[t >> 6] = bv; ri[t >> 6] = bi; }
        __syncthreads();
        if (t == 0) {
            float v0 = rv[0]; int i0 = ri[0];
            for (int w = 1; w < 4; ++w) {
                if (rv[w] < v0 || (rv[w] == v0 && ri[w] < i0)) { v0 = rv[w]; i0 = ri[w]; }
            }
            sel[it] = i0;
            dist[i0] = 3.4e38f;
        }
        __syncthreads();
    }
    if (t < KK) idx_out[((size_t)b * NN + n) * KK + t] = (u16)sel[t];
}

// ---------------------------------------------------------------------------
// Kernel 2: value = MLP_Res(concat(key,query)) in LDS; float4 global staging,
// coalesced transposed weights. Emits vf (B,N,64) and resid (B,N,128) bf16.
// ---------------------------------------------------------------------------
__global__ __launch_bounds__(256) void value_kernel(
    const float* __restrict__ key_feat, const float* __restrict__ query_feat,
    const float* __restrict__ Wv1T, const float* __restrict__ bv1,
    const float* __restrict__ Wv2T, const float* __restrict__ bv2,
    const float* __restrict__ WvsT, const float* __restrict__ bvs,
    const float* __restrict__ WvvT, const float* __restrict__ bvv,
    const float* __restrict__ WresT, const float* __restrict__ bres,
    bf16* __restrict__ vf_ws, bf16* __restrict__ resid_ws) {
    __shared__ __align__(16) float xcol[2 * CIN][8];
    __shared__ __align__(16) float hid[CIN][8];
    __shared__ __align__(16) float val[CIN][8];
    const int b  = blockIdx.x / (NN / 8);
    const int n0 = (blockIdx.x % (NN / 8)) * 8;
    const int t  = threadIdx.x;
    const float* kfp = key_feat + (size_t)b * CIN * NN;
    const float* qfp = query_feat + (size_t)b * CIN * NN;
    // float4 staging: 1024 float4s total, 4 per thread
#pragma unroll
    for (int r = 0; r < 4; ++r) {
        int u = t * 4 + r;             // float4 index; c = u>>1, j0 = (u&1)*4
        int c = u >> 1, j0 = (u & 1) * 4;
        float4 v = (c < CIN) ? *(const float4*)&kfp[(size_t)c * NN + n0 + j0]
                             : *(const float4*)&qfp[(size_t)(c - CIN) * NN + n0 + j0];
        *(float4*)&xcol[c][j0] = v;
    }
    __syncthreads();
    const int o = t;
    float acc[8];
#pragma unroll
    for (int j = 0; j < 8; ++j) acc[j] = 0.f;
    for (int c = 0; c < 2 * CIN; ++c) {
        float w = Wv1T[(size_t)c * CIN + o];
        const float4* x4 = (const float4*)(&xcol[c][0]);
        float4 x0 = x4[0], x1 = x4[1];
        acc[0] += w * x0.x; acc[1] += w * x0.y; acc[2] += w * x0.z; acc[3] += w * x0.w;
        acc[4] += w * x1.x; acc[5] += w * x1.y; acc[6] += w * x1.z; acc[7] += w * x1.w;
    }
    const float b1 = bv1[o];
#pragma unroll
    for (int j = 0; j < 8; ++j) hid[o][j] = fmaxf(acc[j] + b1, 0.f);
    __syncthreads();
    float acc2[8];
#pragma unroll
    for (int j = 0; j < 8; ++j) acc2[j] = 0.f;
    for (int c = 0; c < CIN; ++c) {
        float w = Wv2T[(size_t)c * CIN + o];
        const float4* h4 = (const float4*)(&hid[c][0]);
        float4 h0 = h4[0], h1 = h4[1];
        acc2[0] += w * h0.x; acc2[1] += w * h0.y; acc2[2] += w * h0.z; acc2[3] += w * h0.w;
        acc2[4] += w * h1.x; acc2[5] += w * h1.y; acc2[6] += w * h1.z; acc2[7] += w * h1.w;
    }
    for (int c = 0; c < 2 * CIN; ++c) {
        float w = WvsT[(size_t)c * CIN + o];
        const float4* x4 = (const float4*)(&xcol[c][0]);
        float4 x0 = x4[0], x1 = x4[1];
        acc2[0] += w * x0.x; acc2[1] += w * x0.y; acc2[2] += w * x0.z; acc2[3] += w * x0.w;
        acc2[4] += w * x1.x; acc2[5] += w * x1.y; acc2[6] += w * x1.z; acc2[7] += w * x1.w;
    }
    const float bb = bv2[o] + bvs[o];
#pragma unroll
    for (int j = 0; j < 8; ++j) val[o][j] = acc2[j] + bb;
    __syncthreads();
    {
        const int o2 = t & 63, jg = t >> 6;
        float a0 = 0.f, a1 = 0.f;
        for (int c = 0; c < CIN; ++c) {
            float w = WvvT[(size_t)c * DD + o2];
            a0 += w * val[c][jg];
            a1 += w * val[c][jg + 4];
        }
        const float bo = bvv[o2];
        vf_ws[((size_t)b * NN + n0 + jg) * DD + o2]     = f2bf(a0 + bo);
        vf_ws[((size_t)b * NN + n0 + jg + 4) * DD + o2] = f2bf(a1 + bo);
    }
    {
        const int o3 = t & 127, jg = t >> 7;
        float a0 = 0.f, a1 = 0.f, a2 = 0.f, a3 = 0.f;
        for (int c = 0; c < CIN; ++c) {
            float w = WresT[(size_t)c * COUTN + o3];
            a0 += w * val[c][jg];
            a1 += w * val[c][jg + 2];
            a2 += w * val[c][jg + 4];
            a3 += w * val[c][jg + 6];
        }
        const float bo = bres[o3];
        resid_ws[((size_t)b * NN + n0 + jg) * COUTN + o3]     = f2bf(a0 + bo);
        resid_ws[((size_t)b * NN + n0 + jg + 2) * COUTN + o3] = f2bf(a1 + bo);
        resid_ws[((size_t)b * NN + n0 + jg + 4) * COUTN + o3] = f2bf(a2 + bo);
        resid_ws[((size_t)b * NN + n0 + jg + 6) * COUTN + o3] = f2bf(a3 + bo);
    }
}

// ---------------------------------------------------------------------------
// Kernel 3: kf/qf/uf projections -> (B,N,64) bf16 n-major, transposed weights,
// float4 global staging.
// ---------------------------------------------------------------------------
__global__ __launch_bounds__(256) void proj_kernel(
    const float* __restrict__ key_feat, const float* __restrict__ query_feat,
    const float* __restrict__ upfeat,
    const float* __restrict__ WkT, const float* __restrict__ bk,
    const float* __restrict__ WqT, const float* __restrict__ bq,
    const float* __restrict__ WuT, const float* __restrict__ bu,
    bf16* __restrict__ kf, bf16* __restrict__ qf, bf16* __restrict__ uf) {
    __shared__ __align__(16) float xcol[CIN][16];
    const int p  = blockIdx.y;
    const int b  = blockIdx.x / (NN / 16);
    const int n0 = (blockIdx.x % (NN / 16)) * 16;
    const int t  = threadIdx.x;
    const float* WT; const float* bias; bf16* out; const float* xin;
    if (p == 0)      { WT = WkT; bias = bk; out = kf; xin = key_feat; }
    else if (p == 1) { WT = WqT; bias = bq; out = qf; xin = query_feat; }
    else             { WT = WuT; bias = bu; out = uf; xin = upfeat; }
    const float* xp = xin + (size_t)b * CIN * NN;
#pragma unroll
    for (int r = 0; r < 4; ++r) {
        int u = t * 4 + r;             // float4 index; c = u>>2, j0 = (u&3)*4
        int c = u >> 2, j0 = (u & 3) * 4;
        *(float4*)&xcol[c][j0] = *(const float4*)&xp[(size_t)c * NN + n0 + j0];
    }
    __syncthreads();
    const int o = t & 63, jg = t >> 6;
    float acc[4] = {0.f, 0.f, 0.f, 0.f};
    for (int c = 0; c < CIN; ++c) {
        float w = WT[(size_t)c * DD + o];
        const float4* x4 = (const float4*)(&xcol[c][jg * 4]);
        float4 xv = x4[0];
        acc[0] += w * xv.x; acc[1] += w * xv.y; acc[2] += w * xv.z; acc[3] += w * xv.w;
    }
    const float bb = bias[o];
#pragma unroll
    for (int jj = 0; jj < 4; ++jj)
        out[((size_t)b * NN + n0 + jg * 4 + jj) * DD + o] = f2bf(acc[jj] + bb);
}

// ---------------------------------------------------------------------------
// Kernel 4: fused per-(b,n) attention. Phase F uses k-half split so every
// ds_read_b128 is a single uniform broadcast address per wave; logits go
// through an att buffer overlaid on dead ph/pe scratch.
// ---------------------------------------------------------------------------
__global__ __launch_bounds__(256) void attn_kernel(
    const float* __restrict__ posT, const u16* __restrict__ idx_ws,
    const bf16* __restrict__ kf_ws, const bf16* __restrict__ qf_ws,
    const bf16* __restrict__ uf_ws, const bf16* __restrict__ vf_ws,
    const bf16* __restrict__ resid_ws,
    const float* __restrict__ Wp1, const float* __restrict__ bp1,
    const float* __restrict__ gp1, const float* __restrict__ betap1,
    const float* __restrict__ Wp2T, const float* __restrict__ bp2,
    const float* __restrict__ Wa1T, const float* __restrict__ ba1,
    const float* __restrict__ ga1, const float* __restrict__ betaa1,
    const float* __restrict__ Wt, const float* __restrict__ bt,
    const float* __restrict__ WendT, const float* __restrict__ bend,
    float* __restrict__ out) {
    __shared__ int   nidx[KK];
    __shared__ float prel[KK][3];
    __shared__ float qcol[DD], ucol[DD];
    __shared__ float residc[COUTN];
    __shared__ __align__(16) float scratch[KK * PHH + KK * DD]; // ph | pe ; reused as att
    __shared__ __align__(16) float sbuf[DD][KP];     // 6 KB
    __shared__ __align__(16) float vbuf[DD][KP];     // 6 KB
    __shared__ __align__(16) float hbuf[AHH][KP];    // 24 KB (2 k-halves x 12)
    __shared__ float agg[2 * DD];

    float (*ph)[PHH] = (float(*)[PHH])scratch;
    float (*pe)[DD]  = (float(*)[DD])(scratch + KK * PHH);
    float* att       = scratch;                      // 128*20 = 2560 floats ok

    const int b = blockIdx.x / NN;
    const int n = blockIdx.x % NN;
    const int t = threadIdx.x;
    const size_t row = (size_t)b * NN + n;

    if (t < KK) nidx[t] = (int)idx_ws[row * KK + t];
    __syncthreads();

    // phase A: loads + contiguous gathers
    if (t < DD)                qcol[t]        = bf2f(qf_ws[row * DD + t]);
    else if (t < 2 * DD)       ucol[t - DD]   = bf2f(uf_ws[row * DD + (t - DD)]);
    else                       residc[t - 2 * DD] = bf2f(resid_ws[row * COUTN + (t - 2 * DD)]);
    if (t < KK * 3) {
        int k = t / 3, d = t % 3;
        prel[k][d] = posT[row * 3 + d] - posT[((size_t)b * NN + nidx[k]) * 3 + d];
    }
    for (int u = t; u < KK * DD; u += 256) {
        int k = u >> 6, c = u & 63;
        size_t nb = ((size_t)b * NN + nidx[k]) * DD + c;
        float un = bf2f(uf_ws[nb]);
        sbuf[c][k] = -(bf2f(kf_ws[nb]) + un);
        vbuf[c][k] = bf2f(vf_ws[nb]) - un;
    }
    __syncthreads();

    // phase B: pos_mlp layer 1 (3 -> 64, BN, ReLU)
    for (int u = t; u < KK * PHH; u += 256) {
        int k = u >> 6, c = u & 63;
        float a = Wp1[c * 3 + 0] * prel[k][0]
                + Wp1[c * 3 + 1] * prel[k][1]
                + Wp1[c * 3 + 2] * prel[k][2]
                + bp1[c];
        a = gp1[c] * a * BN_INV + betap1[c];
        ph[k][c] = fmaxf(a, 0.f);
    }
    __syncthreads();

    // phase C: pos_mlp layer 2 (64 -> 64); ph rows read as float4
    for (int u = t; u < KK * DD; u += 256) {
        int k = u >> 6, c = u & 63;
        float a = 0.f;
        const float4* p4 = (const float4*)(&ph[k][0]);
#pragma unroll
        for (int j4 = 0; j4 < PHH / 4; ++j4) {
            float4 pv = p4[j4];
            a += Wp2T[(j4 * 4 + 0) * DD + c] * pv.x;
            a += Wp2T[(j4 * 4 + 1) * DD + c] * pv.y;
            a += Wp2T[(j4 * 4 + 2) * DD + c] * pv.z;
            a += Wp2T[(j4 * 4 + 3) * DD + c] * pv.w;
        }
        pe[k][c] = a + bp2[c];
    }
    __syncthreads();

    // phase D: combine -> s = q - k + pe + (u - un); v = vf_n + pe + (u - un)
    for (int u = t; u < KK * DD; u += 256) {
        int k = u >> 6, c = u & 63;
        float add = ucol[c] + pe[k][c];
        sbuf[c][k] += qcol[c] + add;
        vbuf[c][k] += add;
    }
    __syncthreads();

    // phase E: h = relu(bn(Wa1 @ s + ba1)); one AH-row per thread (uniform
    // broadcast b128 reads). hbuf written as 2 padded k-halves (pads = 0).
    {
        const int hr = t;
        float acc[KK];
#pragma unroll
        for (int k = 0; k < KK; ++k) acc[k] = 0.f;
        for (int c = 0; c < DD; ++c) {
            float wv = Wa1T[c * AHH + hr];
            const float4* s4 = (const float4*)(&sbuf[c][0]);
#pragma unroll
            for (int j = 0; j < 5; ++j) {
                float4 sv = s4[j];
                acc[4 * j + 0] += wv * sv.x;
                acc[4 * j + 1] += wv * sv.y;
                acc[4 * j + 2] += wv * sv.z;
                acc[4 * j + 3] += wv * sv.w;
            }
        }
        const float bb = ba1[hr];
        const float g  = ga1[hr];
        const float be = betaa1[hr];
        float h[KK];
#pragma unroll
        for (int k = 0; k < KK; ++k)
            h[k] = fmaxf(g * (acc[k] + bb) * BN_INV + be, 0.f);
        float4* hrow = (float4*)(&hbuf[hr][0]);
        hrow[0] = make_float4(h[0], h[1], h[2], h[3]);
        hrow[1] = make_float4(h[4], h[5], h[6], h[7]);
        hrow[2] = make_float4(h[8], h[9], 0.f, 0.f);
        hrow[3] = make_float4(h[10], h[11], h[12], h[13]);
        hrow[4] = make_float4(h[14], h[15], h[16], h[17]);
        hrow[5] = make_float4(h[18], h[19], 0.f, 0.f);
    }
    __syncthreads();

    // phase F part 1: logits via k-half split. thread = (cr = t&127,
    // kh = t>>7). Waves are kh-pure -> every b128 read is ONE address.
    {
        const int cr = t & 127;
        const int kh = t >> 7;
        float acc[10];
#pragma unroll
        for (int j = 0; j < 10; ++j) acc[j] = 0.f;
        for (int hh = 0; hh < AHH; ++hh) {
            float wv = Wt[(size_t)hh * 128 + cr];
            const float4* h4 = (const float4*)(&hbuf[hh][kh * 12]);
            float4 h0 = h4[0], h1 = h4[1], h2 = h4[2];
            acc[0] += wv * h0.x; acc[1] += wv * h0.y; acc[2] += wv * h0.z; acc[3] += wv * h0.w;
            acc[4] += wv * h1.x; acc[5] += wv * h1.y; acc[6] += wv * h1.z; acc[7] += wv * h1.w;
            acc[8] += wv * h2.x; acc[9] += wv * h2.y;
        }
        float* ap = att + cr * KK + kh * 10;   // overlays dead ph/pe
#pragma unroll
        for (int j = 0; j < 10; ++j) ap[j] = acc[j];
    }
    __syncthreads();

    // phase F part 2: softmax over k + aggregate (threads 0..127)
    if (t < 128) {
        const int cr = t;
        float a20[KK];
        const float4* a4 = (const float4*)(att + cr * KK);
#pragma unroll
        for (int j = 0; j < 5; ++j) {
            float4 v = a4[j];
            a20[4 * j + 0] = v.x; a20[4 * j + 1] = v.y;
            a20[4 * j + 2] = v.z; a20[4 * j + 3] = v.w;
        }
        const float bb = bt[cr >> 1];
#pragma unroll
        for (int k = 0; k < KK; ++k) a20[k] += bb;
        float m = a20[0];
#pragma unroll
        for (int k = 1; k < KK; ++k) m = fmaxf(m, a20[k]);
        float sum = 0.f;
#pragma unroll
        for (int k = 0; k < KK; ++k) { a20[k] = expf(a20[k] - m); sum += a20[k]; }
        const float invs = 1.f / sum;
        const int c = cr >> 1;
        const float4* v4 = (const float4*)(&vbuf[c][0]);
        float a = 0.f;
#pragma unroll
        for (int j = 0; j < 5; ++j) {
            float4 vv = v4[j];
            a += (a20[4 * j + 0] * invs) * vv.x;
            a += (a20[4 * j + 1] * invs) * vv.y;
            a += (a20[4 * j + 2] * invs) * vv.z;
            a += (a20[4 * j + 3] * invs) * vv.w;
        }
        agg[cr] = a;
    }
    __syncthreads();

    // phase G: conv_end + residual -> f32 out[b][o][2n+r]; WendT coalesced
    {
        const int o = t & 127, r = t >> 7;
        float acc = bend[o];
        for (int c = 0; c < DD; ++c) acc += WendT[c * COUTN + o] * agg[c * 2 + r];
        out[(size_t)b * COUTN * (NN * UPF) + (size_t)o * (NN * UPF) + 2 * n + r] =
            acc + residc[o];
    }
}

extern "C" void kernel_launch(void* const* d_in, const int* in_sizes, int n_in,
                              void* d_out, int out_size, void* d_ws, size_t ws_size,
                              hipStream_t stream) {
    const float* pos        = (const float*)d_in[0];
    const float* key_feat   = (const float*)d_in[1];
    const float* query_feat = (const float*)d_in[2];
    const float* upfeat     = (const float*)d_in[3];
    const float* Wv1 = (const float*)d_in[4];
    const float* bv1 = (const float*)d_in[5];
    const float* Wv2 = (const float*)d_in[6];
    const float* bv2 = (const float*)d_in[7];
    const float* Wvs = (const float*)d_in[8];
    const float* bvs = (const float*)d_in[9];
    const float* Wk  = (const float*)d_in[10];
    const float* bk  = (const float*)d_in[11];
    const float* Wq  = (const float*)d_in[12];
    const float* bq  = (const float*)d_in[13];
    const float* Wvv = (const float*)d_in[14];
    const float* bvv = (const float*)d_in[15];
    const float* Wu  = (const float*)d_in[16];
    const float* bu  = (const float*)d_in[17];
    const float* Wp1 = (const float*)d_in[18];
    const float* bp1 = (const float*)d_in[19];
    const float* gp1 = (const float*)d_in[20];
    const float* betap1 = (const float*)d_in[21];
    const float* Wp2 = (const float*)d_in[22];
    const float* bp2 = (const float*)d_in[23];
    const float* Wa1 = (const float*)d_in[24];
    const float* ba1 = (const float*)d_in[25];
    const float* ga1 = (const float*)d_in[26];
    const float* betaa1 = (const float*)d_in[27];
    const float* Wt   = (const float*)d_in[28];
    const float* bt   = (const float*)d_in[29];
    const float* Wend = (const float*)d_in[30];
    const float* bend = (const float*)d_in[31];
    const float* Wres = (const float*)d_in[32];
    const float* bres = (const float*)d_in[33];
    float* out = (float*)d_out;
    (void)out_size;

    const bool sizes_ok = (n_in >= 34)
        && (in_sizes[0] == BB * 3 * NN)
        && (in_sizes[1] == BB * CIN * NN)
        && (in_sizes[4] == CIN * 2 * CIN)
        && (in_sizes[28] == AHH * DD * UPF)
        && (in_sizes[32] == COUTN * CIN);

    // Workspace layout (256B-aligned), total ~14.7 MB.
    size_t off = 0;
    auto take = [&](size_t bytes) { size_t o = off; off = (off + bytes + 255) & ~(size_t)255; return o; };
    const size_t off_posT  = take((size_t)BB * NN * 3 * sizeof(float));
    const size_t off_idx   = take((size_t)BB * NN * KK * sizeof(u16));
    const size_t off_vf    = take((size_t)BB * NN * DD * sizeof(bf16));
    const size_t off_kf    = take((size_t)BB * NN * DD * sizeof(bf16));
    const size_t off_qf    = take((size_t)BB * NN * DD * sizeof(bf16));
    const size_t off_uf    = take((size_t)BB * NN * DD * sizeof(bf16));
    const size_t off_resid = take((size_t)BB * NN * COUTN * sizeof(bf16));
    const size_t off_wa1t  = take((size_t)AHH * DD * sizeof(float));
    const size_t off_wp2t  = take((size_t)PHH * PHH * sizeof(float));
    const size_t off_wendt = take((size_t)COUTN * DD * sizeof(float));
    const size_t off_wv1t  = take((size_t)CIN * 2 * CIN * sizeof(float));
    const size_t off_wv2t  = take((size_t)CIN * CIN * sizeof(float));
    const size_t off_wvst  = take((size_t)CIN * 2 * CIN * sizeof(float));
    const size_t off_wvvt  = take((size_t)DD * CIN * sizeof(float));
    const size_t off_wrest = take((size_t)COUTN * CIN * sizeof(float));
    const size_t off_wkt   = take((size_t)DD * CIN * sizeof(float));
    const size_t off_wqt   = take((size_t)DD * CIN * sizeof(float));
    const size_t off_wut   = take((size_t)DD * CIN * sizeof(float));
    const size_t NEED = off;

    if (!sizes_ok) return;
    if (ws_size < NEED) {
        sentinel_kernel<<<1, 64, 0, stream>>>(out);
        return;
    }

    char* ws = (char*)d_ws;
    float* posT_ws  = (float*)(ws + off_posT);
    u16*   idx_ws   = (u16*)(ws + off_idx);
    bf16*  vf_ws    = (bf16*)(ws + off_vf);
    bf16*  kf_ws    = (bf16*)(ws + off_kf);
    bf16*  qf_ws    = (bf16*)(ws + off_qf);
    bf16*  uf_ws    = (bf16*)(ws + off_uf);
    bf16*  resid_ws = (bf16*)(ws + off_resid);
    float* Wa1T_ws  = (float*)(ws + off_wa1t);
    float* Wp2T_ws  = (float*)(ws + off_wp2t);
    float* WendT_ws = (float*)(ws + off_wendt);
    float* Wv1T_ws  = (float*)(ws + off_wv1t);
    float* Wv2T_ws  = (float*)(ws + off_wv2t);
    float* WvsT_ws  = (float*)(ws + off_wvst);
    float* WvvT_ws  = (float*)(ws + off_wvvt);
    float* WresT_ws = (float*)(ws + off_wrest);
    float* WkT_ws   = (float*)(ws + off_wkt);
    float* WqT_ws   = (float*)(ws + off_wqt);
    float* WuT_ws   = (float*)(ws + off_wut);

    prep_kernel<<<(CIN * 2 * CIN + 255) / 256, 256, 0, stream>>>(
        Wa1, Wp2, Wend, Wv1, Wv2, Wvs, Wvv, Wres, Wk, Wq, Wu,
        Wa1T_ws, Wp2T_ws, WendT_ws, Wv1T_ws, Wv2T_ws, WvsT_ws,
        WvvT_ws, WresT_ws, WkT_ws, WqT_ws, WuT_ws);
    knn_kernel<<<BB * NN, 256, 0, stream>>>(pos, idx_ws, posT_ws);
    value_kernel<<<BB * (NN / 8), 256, 0, stream>>>(key_feat, query_feat,
        Wv1T_ws, bv1, Wv2T_ws, bv2, WvsT_ws, bvs, WvvT_ws, bvv, WresT_ws, bres,
        vf_ws, resid_ws);
    proj_kernel<<<dim3(BB * (NN / 16), 3), 256, 0, stream>>>(key_feat, query_feat, upfeat,
        WkT_ws, bk, WqT_ws, bq, WuT_ws, bu, kf_ws, qf_ws, uf_ws);
    attn_kernel<<<BB * NN, 256, 0, stream>>>(posT_ws, idx_ws,
        kf_ws, qf_ws, uf_ws, vf_ws, resid_ws,
        Wp1, bp1, gp1, betap1, Wp2T_ws, bp2, Wa1T_ws, ba1, ga1, betaa1, Wt, bt,
        WendT_ws, bend, out);
}